// Round 6
// baseline (157.033 us; speedup 1.0000x reference)
//
#include <hip/hip_runtime.h>

// Problem constants (from reference)
#define DIM    1024
#define N_CLS  10
#define NROWS  16384
#define IMG    784

// K padded to 832 = 26 x 32 (MFMA K-step). ref is zero for k >= 784 so the
// math stays exact while skipping cols 832..1023 of z (18.6% traffic cut).
#define KPAD   832
#define KSTEP  26
#define PF     6     // load-ring depth: 6 steps x 4 KB in flight per wave

using f32x4  = __attribute__((ext_vector_type(4))) float;
using bf16x8 = __attribute__((ext_vector_type(8))) short;
typedef unsigned int u32;
typedef unsigned short u16;

union frag_cast {
  u32 i[4];
  bf16x8 h;
  f32x4 f;
};

// round-to-nearest-even fp32 -> bf16 (values are tame: no NaN/Inf handling)
static __device__ __forceinline__ u16 bf16_rne(float f) {
  u32 u = __float_as_uint(f);
  return (u16)((u + 0x7fffu + ((u >> 16) & 1u)) >> 16);
}

// Split 8 fp32 (two f32x4, ascending k) into bf16 hi (truncate: z = hi + lo
// EXACT in fp32) and bf16 lo (RNE of the residual). hi*B + lo*B recovers
// fp32-grade precision from bf16 MFMAs (residual error ~2^-17 per element).
static __device__ __forceinline__ void split8(const f32x4 v0, const f32x4 v1,
                                              bf16x8& hi, bf16x8& lo) {
  const float f[8] = {v0.x, v0.y, v0.z, v0.w, v1.x, v1.y, v1.z, v1.w};
  frag_cast H, L;
#pragma unroll
  for (int i = 0; i < 4; ++i) {
    const u32 a = __float_as_uint(f[2 * i]);
    const u32 b = __float_as_uint(f[2 * i + 1]);
    H.i[i] = (a >> 16) | (b & 0xffff0000u);
    const float l0 = f[2 * i] - __uint_as_float(a & 0xffff0000u);
    const float l1 = f[2 * i + 1] - __uint_as_float(b & 0xffff0000u);
    u32 p;
    asm("v_cvt_pk_bf16_f32 %0, %1, %2" : "=v"(p) : "v"(l0), "v"(l1));
    L.i[i] = p;
  }
  hi = H.h;
  lo = L.h;
}

// Wave64 DPP sum; result valid in lane 63 (canon normalization only).
__device__ __forceinline__ float wave64_sum(float x) {
#define DPP_ADD(ctrl, rmask, bmask)                                           \
  x += __int_as_float(__builtin_amdgcn_update_dpp(                            \
      0, __float_as_int(x), ctrl, rmask, bmask, true));
  DPP_ADD(0x111, 0xf, 0xf)  // row_shr:1
  DPP_ADD(0x112, 0xf, 0xf)  // row_shr:2
  DPP_ADD(0x114, 0xf, 0xe)  // row_shr:4
  DPP_ADD(0x118, 0xf, 0xc)  // row_shr:8
  DPP_ADD(0x142, 0xa, 0xf)  // row_bcast:15
  DPP_ADD(0x143, 0xc, 0xf)  // row_bcast:31
#undef DPP_ADD
  return x;
}

// ---------------------------------------------------------------------------
// MFMA formulation: S[n,c] = sum_k Z[n,k] * ref[c,k] for Z in {z_re, z_im}.
// Per wave: one 16-row tile, full K sweep (26 MFMA steps), D = 16x16 (10 cols
// used). A-frag (z) from global in fragment layout: lane l reads row (l&15),
// k-bytes (l>>4)*32 + {0,16} per step -> each 128 B line fully consumed by an
// adjacent instr pair. B-frag (ref, split bf16 hi/lo) from LDS: per step 2x
// ds_read_b128, 1024 B contiguous per wave -> conflict-free, amortized over
// 16 rows. No DPP reduction (MFMA reduces k), no per-row ref re-reads.
// ---------------------------------------------------------------------------
__global__ __launch_bounds__(256, 1) void swaptest_kernel(
    const float* __restrict__ zre, const float* __restrict__ zim,
    const float* __restrict__ canon, float* __restrict__ out) {
  // B layout: elem idx ((s*4 + g)*16 + c)*8 + j  for k = s*32 + g*8 + j.
  __shared__ u16 bhi[KSTEP * 4 * 16 * 8];  // 26624 B
  __shared__ u16 blo[KSTEP * 4 * 16 * 8];  // 26624 B
  __shared__ float linv[16];

  const int t = threadIdx.x;
  const int lane = t & 63;
  const int wave = t >> 6;

  // ---- per-class inverse norms (coalesced global reads, L2-hot canon) ----
  for (int c = wave; c < N_CLS; c += 4) {
    float ss = 0.f;
    for (int i = lane; i < IMG; i += 64) {
      const float v = canon[c * IMG + i];
      ss += v * v;
    }
    ss = wave64_sum(ss);
    if (lane == 63) linv[c] = 1.0f / sqrtf(ss);
  }
  __syncthreads();

  // ---- build B (ref^T, zero-padded, split bf16 hi/lo) in LDS ----
  for (int idx = t; idx < KPAD * 16; idx += 256) {
    const int k = idx >> 4;
    const int c = idx & 15;
    float val = 0.f;
    if (c < N_CLS && k < IMG) val = canon[c * IMG + k] * linv[c];
    const int s = k >> 5, g = (k >> 3) & 3, j = k & 7;
    const int pos = ((s * 4 + g) * 16 + c) * 8 + j;
    const u32 u = __float_as_uint(val);
    bhi[pos] = (u16)(u >> 16);
    blo[pos] = bf16_rne(val - __uint_as_float(u & 0xffff0000u));
  }
  __syncthreads();

  // ---- main: one 16-row tile per wave ----
  const int wid = blockIdx.x * 4 + wave;  // 0..1023
  const int row0 = wid * 16;
  const int l15 = lane & 15;   // A row within tile; also D/B col
  const int gr = lane >> 4;    // k-group

  const f32x4* pre = (const f32x4*)(zre + (size_t)(row0 + l15) * DIM) + gr * 2;
  const f32x4* pim = (const f32x4*)(zim + (size_t)(row0 + l15) * DIM) + gr * 2;

  // load ring (all indices static after full unroll)
  f32x4 r0[PF], r1[PF], i0[PF], i1[PF];
#pragma unroll
  for (int j = 0; j < PF; ++j) {
    r0[j] = pre[j * 8];
    r1[j] = pre[j * 8 + 1];
    i0[j] = pim[j * 8];
    i1[j] = pim[j * 8 + 1];
  }

  f32x4 accre = {0.f, 0.f, 0.f, 0.f};
  f32x4 accim = {0.f, 0.f, 0.f, 0.f};

#pragma unroll
  for (int j = 0; j < KSTEP; ++j) {
    const int b = j % PF;
    bf16x8 arh, arl, aih, ail;
    split8(r0[b], r1[b], arh, arl);
    split8(i0[b], i1[b], aih, ail);
    if (j + PF < KSTEP) {
      r0[b] = pre[(j + PF) * 8];
      r1[b] = pre[(j + PF) * 8 + 1];
      i0[b] = pim[(j + PF) * 8];
      i1[b] = pim[(j + PF) * 8 + 1];
    }
    frag_cast BH, BL;
    const int be = (j * 64 + gr * 16 + l15) * 8;  // ushort index, 16B aligned
    BH.f = *(const f32x4*)&bhi[be];
    BL.f = *(const f32x4*)&blo[be];

    accre = __builtin_amdgcn_mfma_f32_16x16x32_bf16(arh, BH.h, accre, 0, 0, 0);
    accre = __builtin_amdgcn_mfma_f32_16x16x32_bf16(arl, BH.h, accre, 0, 0, 0);
    accre = __builtin_amdgcn_mfma_f32_16x16x32_bf16(arh, BL.h, accre, 0, 0, 0);
    accim = __builtin_amdgcn_mfma_f32_16x16x32_bf16(aih, BH.h, accim, 0, 0, 0);
    accim = __builtin_amdgcn_mfma_f32_16x16x32_bf16(ail, BH.h, accim, 0, 0, 0);
    accim = __builtin_amdgcn_mfma_f32_16x16x32_bf16(aih, BL.h, accim, 0, 0, 0);
  }

  // ---- epilogue: D[row,col]: col = lane&15, row = (lane>>4)*4 + i ----
  const int c = l15;
  const int rbase = row0 + gr * 4;
  if (c < N_CLS) {
#pragma unroll
    for (int i = 0; i < 4; ++i) {
      const float sre = accre[i];
      const float sim = accim[i];
      out[(size_t)(rbase + i) * N_CLS + c] = sre * sre + sim * sim;
    }
  }
}

// ---------------------------------------------------------------------------
extern "C" void kernel_launch(void* const* d_in, const int* in_sizes, int n_in,
                              void* d_out, int out_size, void* d_ws,
                              size_t ws_size, hipStream_t stream) {
  const float* z_re = (const float*)d_in[0];
  const float* z_im = (const float*)d_in[1];
  const float* canon = (const float*)d_in[2];
  float* out = (float*)d_out;
  (void)d_ws; (void)ws_size;

  // 1024 tiles of 16 rows, 4 waves/block -> 256 blocks (1 per CU).
  swaptest_kernel<<<NROWS / 16 / 4, 256, 0, stream>>>(z_re, z_im, canon, out);
}

// Round 7
// 154.911 us; speedup vs baseline: 1.0137x; 1.0137x over previous
//
#include <hip/hip_runtime.h>

// Problem constants (from reference)
#define DIM    1024
#define N_CLS  10
#define NROWS  16384
#define IMG    784

// Only z cols [0,832) matter (ref zero-padded beyond 783). Each comp-row is
// staged as 208 f32x4 (cols 0..831) into a 224-f32x4 LDS stride whose last 16
// entries are zeroed once -> k-step 6 reads idx 192..223 with exact zeros in
// the tail. Math stays EXACT.
#define NF4    196   // nonzero f32x4 of ref (784/4)
#define NLOAD  208   // f32x4 staged per comp-row (cols 0..831)
#define NPAD   224   // comp-row stride in f32x4 (16 zero-padded)
#define NSTEP  7     // k-steps of 32 f32x4
#define WAVES  4
#define RP     8     // row-pairs (pipeline iterations) per wave
#define ROWS_PER_BLK (WAVES * 2 * RP)  // 64 -> 256 blocks, 1/CU

typedef float f32x4 __attribute__((ext_vector_type(4)));
typedef float f32x2 __attribute__((ext_vector_type(2)));

static __device__ __forceinline__ f32x2 lo2(f32x4 v) {
  return __builtin_shufflevector(v, v, 0, 1);
}
static __device__ __forceinline__ f32x2 hi2(f32x4 v) {
  return __builtin_shufflevector(v, v, 2, 3);
}

// Packed dual-FP32 FMA; compiler won't form it from scalar code.
static __device__ __forceinline__ void pk_fma(f32x2& acc, f32x2 a, f32x2 b) {
  asm("v_pk_fma_f32 %0, %1, %2, %0" : "+v"(acc) : "v"(a), "v"(b));
}

// Async global->LDS (fire-and-forget, vmcnt-counted, zero VGPR cost).
// LDS dst must be wave-uniform (HW adds lane*16); global src is per-lane.
#define ASYNC16(lds, g)                                                       \
  __builtin_amdgcn_global_load_lds(                                           \
      (const __attribute__((address_space(1))) unsigned int*)(g),             \
      (__attribute__((address_space(3))) unsigned int*)(lds), 16, 0, 0)

// ---------------------------------------------------------------------------
// DPP reductions. bound_ctrl=1: masked/invalid lanes contribute 0.
// ---------------------------------------------------------------------------
#define DPP_ADD(ctrl, rmask, bmask)                                           \
  x += __int_as_float(__builtin_amdgcn_update_dpp(                            \
      0, __float_as_int(x), ctrl, rmask, bmask, true));

__device__ __forceinline__ float wave64_sum(float x) {
  DPP_ADD(0x111, 0xf, 0xf)  // row_shr:1
  DPP_ADD(0x112, 0xf, 0xf)  // row_shr:2
  DPP_ADD(0x114, 0xf, 0xe)  // row_shr:4
  DPP_ADD(0x118, 0xf, 0xc)  // row_shr:8
  DPP_ADD(0x142, 0xa, 0xf)  // row_bcast:15
  DPP_ADD(0x143, 0xc, 0xf)  // row_bcast:31
  return x;  // total in lane 63
}

// 32-lane group sum; results valid in lanes 31 and 63.
__device__ __forceinline__ float group32_sum(float x) {
  DPP_ADD(0x111, 0xf, 0xf)
  DPP_ADD(0x112, 0xf, 0xf)
  DPP_ADD(0x114, 0xf, 0xe)
  DPP_ADD(0x118, 0xf, 0xc)
  DPP_ADD(0x142, 0xa, 0xf)  // row_bcast:15 -> lanes 31/63 hold 32-lane sums
  return x;
}
#undef DPP_ADD

// ---------------------------------------------------------------------------
// Kernel: ref normalized into LDS once; then each wave runs a private
// double-buffered async pipeline: stage row-pair q+1 via global_load_lds
// while computing row-pair q from LDS. No barriers in the main loop; per-wave
// counted "s_waitcnt vmcnt(16)" keeps exactly one 14 KB slot in flight at all
// times -> ~57-110 KB outstanding per CU, structurally (not VGPR-dependent).
// ---------------------------------------------------------------------------
__global__ __launch_bounds__(256, 1) void swaptest_kernel(
    const float* __restrict__ zre, const float* __restrict__ zim,
    const float* __restrict__ canon, float* __restrict__ out) {
  // [wave][slot][comp-row: r0re,r0im,r1re,r1im][NPAD]
  __shared__ f32x4 zbuf[WAVES][2][4][NPAD];  // 114688 B
  __shared__ f32x4 lref[N_CLS * NPAD];       //  35840 B  (total 150528 B)

  const int t = threadIdx.x;
  const int lane = t & 63;
  const int wave = t >> 6;

  // ---- zero the 16-f32x4 tail pad of every comp-row slot (once) ----
  for (int i = t; i < WAVES * 2 * 4 * 16; i += 256) {
    const int w = i >> 7, rem = i & 127;
    const int sl = rem >> 6, cr = (rem >> 4) & 3, e = rem & 15;
    zbuf[w][sl][cr][NLOAD + e] = (f32x4){0.f, 0.f, 0.f, 0.f};
  }

  // ---- stage canon -> lref (zero-padded beyond f32x4 idx 196) ----
#pragma unroll
  for (int c = 0; c < N_CLS; ++c) {
    if (t < NPAD) {
      f32x4 v = {0.f, 0.f, 0.f, 0.f};
      if (t < NF4) v = ((const f32x4*)canon)[c * NF4 + t];
      lref[c * NPAD + t] = v;
    }
  }
  __syncthreads();

  // ---- normalize each class in LDS (wave w: classes w, w+4, w+8) ----
  for (int c = wave; c < N_CLS; c += WAVES) {
    float ss = 0.f;
    for (int i = lane; i < NPAD; i += 64) {
      f32x4 v = lref[c * NPAD + i];
      ss += v.x * v.x + v.y * v.y + v.z * v.z + v.w * v.w;
    }
    ss = wave64_sum(ss);                       // lane 63
    float inv = __shfl(1.0f / sqrtf(ss), 63);  // broadcast
    for (int i = lane; i < NPAD; i += 64) {
      f32x4 v = lref[c * NPAD + i];
      v.x *= inv; v.y *= inv; v.z *= inv; v.w *= inv;
      lref[c * NPAD + i] = v;
    }
  }
  __syncthreads();

  // ---- async pipeline ----
  const int s = lane & 31;
  const int g = lane >> 5;
  const int brow = blockIdx.x * ROWS_PER_BLK;

  // stage one comp-row: 3 full + 1 quarter-masked async16 = 4 vmcnt events
  auto stage_row = [&](f32x4* dst, const float* src) {
    const char* gp = (const char*)src;
#pragma unroll
    for (int i = 0; i < 3; ++i)
      ASYNC16(&dst[i * 64], gp + (size_t)(i * 64 + lane) * 16);
    if (lane < 16) ASYNC16(&dst[192], gp + (size_t)(192 + lane) * 16);
  };
  // stage one row-pair (16 vmcnt events)
  auto stage_pair = [&](int slot, int q) {
    const int r0 = brow + q * (WAVES * 2) + wave * 2;
    stage_row(&zbuf[wave][slot][0][0], zre + (size_t)r0 * DIM);
    stage_row(&zbuf[wave][slot][1][0], zim + (size_t)r0 * DIM);
    stage_row(&zbuf[wave][slot][2][0], zre + (size_t)(r0 + 1) * DIM);
    stage_row(&zbuf[wave][slot][3][0], zim + (size_t)(r0 + 1) * DIM);
  };

  stage_pair(0, 0);
  stage_pair(1, 1);

  for (int r = 0; r < RP; ++r) {
    // Wait for this slot's 16 loads (allow next slot's 16 to stay in flight).
    asm volatile("s_waitcnt vmcnt(16)" ::: "memory");
    __builtin_amdgcn_sched_barrier(0);

    const int slot = r & 1;
    const f32x4* zr_p = &zbuf[wave][slot][g * 2 + 0][0];
    const f32x4* zi_p = &zbuf[wave][slot][g * 2 + 1][0];

    f32x2 accr[N_CLS], acci[N_CLS];
#pragma unroll
    for (int c = 0; c < N_CLS; ++c) {
      accr[c] = (f32x2){0.f, 0.f};
      acci[c] = (f32x2){0.f, 0.f};
    }

#pragma unroll
    for (int j = 0; j < NSTEP; ++j) {
      const f32x4 zr = zr_p[j * 32 + s];
      const f32x4 zi = zi_p[j * 32 + s];
#pragma unroll
      for (int c = 0; c < N_CLS; ++c) {
        const f32x4 rv = lref[c * NPAD + j * 32 + s];  // 2-way broadcast
        pk_fma(accr[c], lo2(zr), lo2(rv));
        pk_fma(accr[c], hi2(zr), hi2(rv));
        pk_fma(acci[c], lo2(zi), lo2(rv));
        pk_fma(acci[c], hi2(zi), hi2(rv));
      }
    }

    const int row0 = brow + r * (WAVES * 2) + wave * 2;
#pragma unroll
    for (int c = 0; c < N_CLS; ++c) {
      float sr = group32_sum(accr[c].x + accr[c].y);
      float si = group32_sum(acci[c].x + acci[c].y);
      if (s == 31) {
        out[(size_t)(row0 + g) * N_CLS + c] = sr * sr + si * si;
      }
    }

    // Refill this slot: pair r+2; at r==RP-2 restage pair RP-2 (dummy, keeps
    // the vmcnt ledger uniform so vmcnt(16) stays exact); none at r==RP-1.
    __builtin_amdgcn_sched_barrier(0);
    if (r <= RP - 2) {
      const int q = (r <= RP - 3) ? (r + 2) : (RP - 2);
      stage_pair(slot, q);
    }
    __builtin_amdgcn_sched_barrier(0);
  }

  // Drain outstanding async loads before LDS deallocation at wave end.
  asm volatile("s_waitcnt vmcnt(0)" ::: "memory");
}

// ---------------------------------------------------------------------------
extern "C" void kernel_launch(void* const* d_in, const int* in_sizes, int n_in,
                              void* d_out, int out_size, void* d_ws,
                              size_t ws_size, hipStream_t stream) {
  const float* z_re = (const float*)d_in[0];
  const float* z_im = (const float*)d_in[1];
  const float* canon = (const float*)d_in[2];
  float* out = (float*)d_out;
  (void)d_ws; (void)ws_size;

  const int nblk = NROWS / ROWS_PER_BLK;  // 256 blocks = 1 per CU
  swaptest_kernel<<<nblk, 64 * WAVES, 0, stream>>>(z_re, z_im, canon, out);
}

// Round 8
// 154.706 us; speedup vs baseline: 1.0150x; 1.0013x over previous
//
#include <hip/hip_runtime.h>

// Problem constants (from reference)
#define DIM     1024
#define N_CLS   10
#define NROWS   16384
#define IMG     784

// ref[c][d] == 0 for d >= 784 (zero-padded reference), so z cols >= 784
// contribute nothing. We now read EXACTLY cols [0,784): 196 f32x4 per row =
// 12 full 16-sublane steps + one step masked to sublanes s<4. LDS ref is
// zero-padded to 208 f32x4 so the masked step's ds_reads stay valid; masked
// lanes keep exact-zero z. Math stays EXACT; z traffic = 102.76 MB (-5.8%
// vs the previous 832-col tiling, -23.3% vs the full 1024).
#define NF4      196   // f32x4 per row actually read (784/4)
#define NF4_PAD  208   // 13 * 16 (LDS zero tail)
#define NSTEP    13
#define LSTRIDE  208   // f32x4 stride per class in LDS (33280 B total)

#define ROWS_PER_BLK 16  // 4 waves x 4 rows (one row per 16-lane group)

// Rolling prefetch ring depth (pairs of re/im loads).
#define PF_DEPTH 6

typedef float f32x4 __attribute__((ext_vector_type(4)));
typedef float f32x2 __attribute__((ext_vector_type(2)));

static __device__ __forceinline__ f32x2 lo2(f32x4 v) {
  return __builtin_shufflevector(v, v, 0, 1);
}
static __device__ __forceinline__ f32x2 hi2(f32x4 v) {
  return __builtin_shufflevector(v, v, 2, 3);
}

// Packed dual-FP32 FMA; compiler won't form it from scalar code.
static __device__ __forceinline__ void pk_fma(f32x2& acc, f32x2 a, f32x2 b) {
  asm("v_pk_fma_f32 %0, %1, %2, %0" : "+v"(acc) : "v"(a), "v"(b));
}

// ---------------------------------------------------------------------------
// DPP reductions. bound_ctrl=1: masked/invalid lanes contribute 0.
// ---------------------------------------------------------------------------
#define DPP_ADD(ctrl, rmask, bmask)                                           \
  x += __int_as_float(__builtin_amdgcn_update_dpp(                            \
      0, __float_as_int(x), ctrl, rmask, bmask, true));

// Full-wave sum; result valid in lane 63 (canon normalization only).
__device__ __forceinline__ float wave64_sum(float x) {
  DPP_ADD(0x111, 0xf, 0xf)  // row_shr:1
  DPP_ADD(0x112, 0xf, 0xf)  // row_shr:2
  DPP_ADD(0x114, 0xf, 0xe)  // row_shr:4
  DPP_ADD(0x118, 0xf, 0xc)  // row_shr:8
  DPP_ADD(0x142, 0xa, 0xf)  // row_bcast:15
  DPP_ADD(0x143, 0xc, 0xf)  // row_bcast:31
  return x;
}

// Sum within each 16-lane DPP row; result valid in lane 15 of each row.
__device__ __forceinline__ float group16_sum(float x) {
  DPP_ADD(0x111, 0xf, 0xf)  // row_shr:1
  DPP_ADD(0x112, 0xf, 0xf)  // row_shr:2
  DPP_ADD(0x114, 0xf, 0xf)  // row_shr:4
  DPP_ADD(0x118, 0xf, 0xf)  // row_shr:8
  return x;
}
#undef DPP_ADD

// ---------------------------------------------------------------------------
// Single fused kernel: stage canon -> LDS (zero-padded), normalize in LDS,
// then swap-test 16 rows per block. Lane (g,s): group g owns row row0+g,
// sublane s owns f32x4 column s+16j. All z loads and ds_reads are one base
// vaddr + imm offsets.
// ---------------------------------------------------------------------------
__global__ __launch_bounds__(256, 4) void swaptest_kernel(
    const float* __restrict__ zre, const float* __restrict__ zim,
    const float* __restrict__ canon, float* __restrict__ out) {
  __shared__ f32x4 lref[N_CLS * LSTRIDE];  // 33280 B -> 4 blocks/CU

  const int t = threadIdx.x;
  const int lane = t & 63;
  const int wave = t >> 6;

  // ---- stage canon (zero-padding f32x4 idx >= 196) ----
#pragma unroll
  for (int c = 0; c < N_CLS; ++c) {
    if (t < NF4_PAD) {
      f32x4 v = {0.f, 0.f, 0.f, 0.f};
      if (t < NF4) v = ((const f32x4*)canon)[c * NF4 + t];
      lref[c * LSTRIDE + t] = v;
    }
  }
  __syncthreads();

  // ---- normalize each class in LDS (wave w handles classes w, w+4, w+8) ----
  for (int c = wave; c < N_CLS; c += 4) {
    float ss = 0.f;
    for (int i = lane; i < NF4_PAD; i += 64) {
      f32x4 v = lref[c * LSTRIDE + i];
      ss += v.x * v.x + v.y * v.y + v.z * v.z + v.w * v.w;
    }
    ss = wave64_sum(ss);                       // lane 63
    float inv = __shfl(1.0f / sqrtf(ss), 63);  // broadcast
    for (int i = lane; i < NF4_PAD; i += 64) {
      f32x4 v = lref[c * LSTRIDE + i];
      v.x *= inv; v.y *= inv; v.z *= inv; v.w *= inv;
      lref[c * LSTRIDE + i] = v;
    }
  }
  __syncthreads();

  // ---- swap test ----
  const int s = lane & 15;
  const int g = lane >> 4;
  const int row = blockIdx.x * ROWS_PER_BLK + wave * 4 + g;

  const f32x4* pr = (const f32x4*)(zre + ((size_t)row << 10)) + s;
  const f32x4* pi = (const f32x4*)(zim + ((size_t)row << 10)) + s;

  f32x2 accr[N_CLS], acci[N_CLS];
#pragma unroll
  for (int c = 0; c < N_CLS; ++c) {
    accr[c] = (f32x2){0.f, 0.f};
    acci[c] = (f32x2){0.f, 0.f};
  }

  // Rolling prefetch ring; all indices compile-time after unroll.
  // Steps 0..11 are full; step 12 loads only sublanes s<4 (f32x4 idx
  // 192..195 = cols 768..783); other lanes keep exact zeros.
  f32x4 bzr[PF_DEPTH], bzi[PF_DEPTH];
#pragma unroll
  for (int j = 0; j < PF_DEPTH; ++j) {  // j = 0..5, all full steps
    bzr[j] = pr[j * 16];
    bzi[j] = pi[j * 16];
  }

#pragma unroll
  for (int j = 0; j < NSTEP; ++j) {
    const int b = j % PF_DEPTH;
    const f32x4 zr = bzr[b];
    const f32x4 zi = bzi[b];
    const int jj = j + PF_DEPTH;
    if (jj < NSTEP) {
      if (jj < NSTEP - 1 || s < 4) {
        bzr[b] = pr[jj * 16];  // byte offset jj*256, imm-foldable
        bzi[b] = pi[jj * 16];
      } else {
        bzr[b] = (f32x4){0.f, 0.f, 0.f, 0.f};
        bzi[b] = (f32x4){0.f, 0.f, 0.f, 0.f};
      }
    }
#pragma unroll
    for (int c = 0; c < N_CLS; ++c) {
      // 4-way broadcast across groups (same address) -> conflict-free.
      const f32x4 rv = lref[c * LSTRIDE + j * 16 + s];
      pk_fma(accr[c], lo2(zr), lo2(rv));
      pk_fma(accr[c], hi2(zr), hi2(rv));
      pk_fma(acci[c], lo2(zi), lo2(rv));
      pk_fma(acci[c], hi2(zi), hi2(rv));
    }
  }

  // 16-lane reductions; totals land in lane 15 of each group.
#pragma unroll
  for (int c = 0; c < N_CLS; ++c) {
    float sr = group16_sum(accr[c].x + accr[c].y);
    float si = group16_sum(acci[c].x + acci[c].y);
    if (s == 15) {
      out[(size_t)row * N_CLS + c] = sr * sr + si * si;
    }
  }
}

// ---------------------------------------------------------------------------
extern "C" void kernel_launch(void* const* d_in, const int* in_sizes, int n_in,
                              void* d_out, int out_size, void* d_ws,
                              size_t ws_size, hipStream_t stream) {
  const float* z_re = (const float*)d_in[0];
  const float* z_im = (const float*)d_in[1];
  const float* canon = (const float*)d_in[2];
  float* out = (float*)d_out;
  (void)d_ws; (void)ws_size;

  const int nblk = NROWS / ROWS_PER_BLK;  // 1024 blocks, 4/CU, one round
  swaptest_kernel<<<nblk, 256, 0, stream>>>(z_re, z_im, canon, out);
}